// Round 1
// 1091.003 us; speedup vs baseline: 1.1237x; 1.1237x over previous
//
#include <hip/hip_runtime.h>
#include <cstdint>

#define BATCH 64
#define SEQ   512
#define DIM   768
#define HEADS 12
#define KEEP  254      // index - 2
#define NOUT  256
#define KOTHER 257     // SEQ - index + 1
#define WCHUNK 8       // weighted-sum split per batch

typedef float vf4 __attribute__((ext_vector_type(4)));

// ---------------- K1: partial column sums over atten ----------------
// grid = BATCH*HEADS*4 blocks (bh*4 + rowchunk), 128 threads, each thread
// owns 4 consecutive columns (float4), sums 128 rows. Coalesced, streaming,
// non-temporal reads (atten has zero reuse -> don't thrash L2).
__global__ void k1_colsum(const float* __restrict__ atten, vf4* __restrict__ partial) {
    int bid = blockIdx.x;            // bh*4 + chunk
    int t   = threadIdx.x;           // 0..127
    int bh  = bid >> 2;
    int row0 = (bid & 3) << 7;       // chunk * 128
    const vf4* A4 = (const vf4*)(atten + (size_t)bh * SEQ * SEQ);
    const vf4* p  = A4 + (size_t)row0 * (SEQ / 4) + t;
    vf4 s = {0.f, 0.f, 0.f, 0.f};
#pragma unroll 8
    for (int r = 0; r < 128; ++r) {
        vf4 v = __builtin_nontemporal_load(&p[(size_t)r * (SEQ / 4)]);
        s.x += v.x; s.y += v.y; s.z += v.z; s.w += v.w;
    }
    partial[(size_t)bid * (SEQ / 4) + t] = s;
}

// ---------------- K23: reduce partials + diag + selection + softmax ----------------
// One block per batch, SEQ threads. ab arithmetic is BIT-IDENTICAL to the
// previous k2 (same summation order), so the selected index sets are
// unchanged. Rank loop vectorized (float4 LDS reads); prefix-count via
// __ballot; max/sum reductions via wave shuffles (order-independent max;
// sum re-association perturbs softmax denom by ~1e-7 rel — within tolerance).
__global__ void k23_select(const float* __restrict__ partial,
                           const float* __restrict__ atten,
                           int* __restrict__ srcidx,
                           int* __restrict__ otheridx,
                           float* __restrict__ otherw) {
    __shared__ __align__(16) float sab[SEQ];
    __shared__ int   wsum[8];
    __shared__ float wred[8];
    int b = blockIdx.x;
    int j = threadIdx.x;
    int lane = j & 63;
    int w = j >> 6;

    float s = 0.f;
#pragma unroll
    for (int c = 0; c < 48; ++c)
        s += partial[((size_t)(b * 48 + c)) * SEQ + j];
    float d = 0.f;
#pragma unroll
    for (int h = 0; h < HEADS; ++h)
        d += atten[((size_t)(b * HEADS + h)) * SEQ * SEQ + (size_t)j * (SEQ + 1)];
    float v = (s - d) / 12.0f;
    sab[j] = v;
    __syncthreads();

    // exact rank with JAX top_k tie-break (value desc, index asc)
    int r = 0;
    if (j >= 1) {
#pragma unroll 4
        for (int k4 = 0; k4 < SEQ; k4 += 4) {
            float4 u = *(const float4*)&sab[k4];
            r += (u.x > v) || (u.x == v && (k4 + 0) < j);
            r += (u.y > v) || (u.y == v && (k4 + 1) < j);
            r += (u.z > v) || (u.z == v && (k4 + 2) < j);
            r += (u.w > v) || (u.w == v && (k4 + 3) < j);
        }
        float u0 = sab[0];                   // remove k=0 term (orig loop starts k=1)
        r -= (u0 > v) || (u0 == v);          // 0 < j always true here
    }
    int keep = (j >= 1) && (r < KEEP);

    // cnt = number of kept tokens with index < j (thread 0 has keep=0)
    unsigned long long m = __ballot(keep);
    if (lane == 0) wsum[w] = (int)__popcll(m);
    int cnt = __popcll(m & ((1ull << lane) - 1ull));
    __syncthreads();
    for (int i = 0; i < w; ++i) cnt += wsum[i];

    // max over "other" set (order-independent)
    float ov = (j >= 1 && !keep) ? v : -3.4e38f;
    for (int off = 32; off; off >>= 1) ov = fmaxf(ov, __shfl_xor(ov, off));
    if (lane == 0) wred[w] = ov;
    __syncthreads();
    float mmax = wred[0];
#pragma unroll
    for (int i = 1; i < 8; ++i) mmax = fmaxf(mmax, wred[i]);

    float e = (j >= 1 && !keep) ? expf(v - mmax) : 0.f;
    float es = e;
    for (int off = 32; off; off >>= 1) es += __shfl_xor(es, off);
    __syncthreads();                          // all mmax reads done before reuse
    if (lane == 0) wred[w] = es;
    __syncthreads();
    float se = 0.f;
#pragma unroll
    for (int i = 0; i < 8; ++i) se += wred[i];

    if (j == 0) srcidx[b * NOUT] = 0;         // cls token always first
    if (j >= 1) {
        if (keep) {
            srcidx[b * NOUT + 1 + cnt] = j;   // positions 1..254, ascending j
        } else {
            int q = (j - 1) - cnt;            // 0..256, ascending j
            otheridx[b * KOTHER + q] = j;
            otherw[b * KOTHER + q] = e / se;
        }
    }
}

// ---------------- K4: gather rows + weighted partial sums ----------------
// blocks [0, BATCH*256): row copies (p==255 blocks no-op).
// blocks [BATCH*256, BATCH*256 + BATCH*8): weighted-sum chunks — 8 blocks
// per batch, each accumulates 32-33 of the 257 terms at full HBM BW.
__global__ void k4_out(const float* __restrict__ x,
                       const int* __restrict__ srcidx,
                       const int* __restrict__ otheridx,
                       const float* __restrict__ otherw,
                       float* __restrict__ out,
                       float* __restrict__ wpart) {
    int blk = blockIdx.x;
    int t = threadIdx.x;             // 0..191
    const float4* x4 = (const float4*)x;
    if (blk < BATCH * NOUT) {
        int b = blk >> 8;
        int p = blk & 255;
        if (p == 255) return;        // written by k5
        int j = srcidx[blk];
        ((float4*)out)[(size_t)blk * 192 + t] = x4[((size_t)b * SEQ + j) * 192 + t];
    } else {
        int widx = blk - BATCH * NOUT;   // 0..511
        int b = widx >> 3;
        int c = widx & 7;
        int q0 = c ? 32 * c + 1 : 0;     // chunk 0: 33 terms, chunks 1..7: 32
        int qn = c ? 32 : 33;
        float4 acc = {0.f, 0.f, 0.f, 0.f};
        for (int q = q0; q < q0 + qn; ++q) {
            int   jj = otheridx[b * KOTHER + q];
            float ww = otherw[b * KOTHER + q];
            float4 xv = x4[((size_t)b * SEQ + jj) * 192 + t];
            acc.x += ww * xv.x; acc.y += ww * xv.y;
            acc.z += ww * xv.z; acc.w += ww * xv.w;
        }
        ((float4*)wpart)[(size_t)widx * 192 + t] = acc;
    }
}

// ---------------- K5: combine weighted partials into out row 255 ----------------
__global__ void k5_combine(const float* __restrict__ wpart, float* __restrict__ out) {
    int b = blockIdx.x;
    int t = threadIdx.x;             // 0..191
    const float4* wp4 = (const float4*)wpart;
    float4 a = {0.f, 0.f, 0.f, 0.f};
#pragma unroll
    for (int c = 0; c < WCHUNK; ++c) {
        float4 v = wp4[((size_t)(b * WCHUNK + c)) * 192 + t];
        a.x += v.x; a.y += v.y; a.z += v.z; a.w += v.w;
    }
    const float inv = 1.0f / 257.0f;
    float4 o = {a.x * inv, a.y * inv, a.z * inv, a.w * inv};
    ((float4*)out)[((size_t)(b * NOUT + 255)) * 192 + t] = o;
}

extern "C" void kernel_launch(void* const* d_in, const int* in_sizes, int n_in,
                              void* d_out, int out_size, void* d_ws, size_t ws_size,
                              hipStream_t stream) {
    const float* x     = (const float*)d_in[0];
    const float* atten = (const float*)d_in[1];
    float* out = (float*)d_out;
    char* ws = (char*)d_ws;

    // ws layout (all fully overwritten before read; no init needed)
    float* partial  = (float*)ws;                                   // 3072*512*4 = 6291456 B
    int*   srcidx   = (int*)(ws + 6291456);                         // 64*256*4   = 65536 B
    int*   otheridx = (int*)(ws + 6291456 + 65536);                 // 64*257*4   = 65792 B
    float* otherw   = (float*)(ws + 6291456 + 65536 + 65792);       // 65792 B
    float* wpart    = (float*)(ws + 6291456 + 65536 + 65792 + 65792); // 512*768*4 = 1572864 B

    k1_colsum<<<dim3(BATCH * HEADS * 4), dim3(128), 0, stream>>>(atten, (vf4*)partial);
    k23_select<<<dim3(BATCH), dim3(SEQ), 0, stream>>>(partial, atten, srcidx, otheridx, otherw);
    k4_out<<<dim3(BATCH * NOUT + BATCH * WCHUNK), dim3(192), 0, stream>>>(
        x, srcidx, otheridx, otherw, out, wpart);
    k5_combine<<<dim3(BATCH), dim3(192), 0, stream>>>(wpart, out);
}

// Round 3
// 1070.443 us; speedup vs baseline: 1.1453x; 1.0192x over previous
//
#include <hip/hip_runtime.h>
#include <cstdint>

#define BATCH 64
#define SEQ   512
#define DIM   768
#define HEADS 12
#define KEEP  254      // index - 2
#define NOUT  256
#define KOTHER 257     // SEQ - index + 1
#define WCHUNK 8       // weighted-sum split per batch

typedef float vf4 __attribute__((ext_vector_type(4)));

// ---------------- K1: partial column sums + diagonal extraction ----------------
// grid = BATCH*HEADS*4 blocks (bh*4 + rowchunk), 128 threads, each thread
// owns 4 consecutive columns (float4), sums 128 rows. Coalesced, streaming,
// non-temporal reads (atten has zero reuse). The diagonal element of row R
// (col R) is owned by thread t=R>>2 component R&3 — capture it in-loop
// (4 cndmasks/iter, free: kernel is HBM-bound at VALUBusy~5%) and write a
// coalesced vf4 to dpart. Values bit-identical to reading atten[j][j].
__global__ void k1_colsum(const float* __restrict__ atten, vf4* __restrict__ partial,
                          float* __restrict__ dpart) {
    int bid = blockIdx.x;            // bh*4 + chunk
    int t   = threadIdx.x;           // 0..127
    int bh  = bid >> 2;
    int row0 = (bid & 3) << 7;       // chunk * 128
    const vf4* A4 = (const vf4*)(atten + (size_t)bh * SEQ * SEQ);
    const vf4* p  = A4 + (size_t)row0 * (SEQ / 4) + t;
    int base = (t << 2) - row0;      // loop index r at which col group 4t..4t+3 meets the diagonal
    float d0 = 0.f, d1 = 0.f, d2 = 0.f, d3 = 0.f;
    vf4 s = {0.f, 0.f, 0.f, 0.f};
#pragma unroll 8
    for (int r = 0; r < 128; ++r) {
        vf4 v = __builtin_nontemporal_load(&p[(size_t)r * (SEQ / 4)]);
        s.x += v.x; s.y += v.y; s.z += v.z; s.w += v.w;
        int rb = r - base;
        d0 = (rb == 0) ? v.x : d0;   // row 4t+0, col 4t+0
        d1 = (rb == 1) ? v.y : d1;   // row 4t+1, col 4t+1
        d2 = (rb == 2) ? v.z : d2;
        d3 = (rb == 3) ? v.w : d3;
    }
    partial[(size_t)bid * (SEQ / 4) + t] = s;
    if ((unsigned)base < 128u) {     // this thread's 4 diag rows live in this chunk
        vf4 dv = {d0, d1, d2, d3};
        *(vf4*)&dpart[(size_t)bh * SEQ + (t << 2)] = dv;
    }
}

// ---------------- K23: reduce partials + diag + selection + softmax ----------------
// One block per batch, SEQ threads. ab arithmetic bit-identical to the
// original k2 (same values, same summation order), so selected index sets
// are unchanged. Diagonal now comes from dpart (coalesced), not scattered
// atten reads.
__global__ void k23_select(const float* __restrict__ partial,
                           const float* __restrict__ dpart,
                           int* __restrict__ srcidx,
                           int* __restrict__ otheridx,
                           float* __restrict__ otherw) {
    __shared__ __align__(16) float sab[SEQ];
    __shared__ int   wsum[8];
    __shared__ float wred[8];
    int b = blockIdx.x;
    int j = threadIdx.x;
    int lane = j & 63;
    int w = j >> 6;

    float s = 0.f;
#pragma unroll
    for (int c = 0; c < 48; ++c)
        s += __builtin_nontemporal_load(&partial[((size_t)(b * 48 + c)) * SEQ + j]);
    float d = 0.f;
#pragma unroll
    for (int h = 0; h < HEADS; ++h)
        d += dpart[((size_t)(b * HEADS + h)) * SEQ + j];
    float v = (s - d) / 12.0f;
    sab[j] = v;
    __syncthreads();

    // exact rank with JAX top_k tie-break (value desc, index asc)
    int r = 0;
    if (j >= 1) {
#pragma unroll 4
        for (int k4 = 0; k4 < SEQ; k4 += 4) {
            vf4 u = *(const vf4*)&sab[k4];
            r += (u.x > v) || (u.x == v && (k4 + 0) < j);
            r += (u.y > v) || (u.y == v && (k4 + 1) < j);
            r += (u.z > v) || (u.z == v && (k4 + 2) < j);
            r += (u.w > v) || (u.w == v && (k4 + 3) < j);
        }
        float u0 = sab[0];                   // remove k=0 term (orig loop starts k=1)
        r -= (u0 > v) || (u0 == v);          // 0 < j always true here
    }
    int keep = (j >= 1) && (r < KEEP);

    // cnt = number of kept tokens with index < j (thread 0 has keep=0)
    unsigned long long m = __ballot(keep);
    if (lane == 0) wsum[w] = (int)__popcll(m);
    int cnt = __popcll(m & ((1ull << lane) - 1ull));
    __syncthreads();
    for (int i = 0; i < w; ++i) cnt += wsum[i];

    // max over "other" set (order-independent)
    float ov = (j >= 1 && !keep) ? v : -3.4e38f;
    for (int off = 32; off; off >>= 1) ov = fmaxf(ov, __shfl_xor(ov, off));
    if (lane == 0) wred[w] = ov;
    __syncthreads();
    float mmax = wred[0];
#pragma unroll
    for (int i = 1; i < 8; ++i) mmax = fmaxf(mmax, wred[i]);

    float e = (j >= 1 && !keep) ? expf(v - mmax) : 0.f;
    float es = e;
    for (int off = 32; off; off >>= 1) es += __shfl_xor(es, off);
    __syncthreads();                          // all mmax reads done before reuse
    if (lane == 0) wred[w] = es;
    __syncthreads();
    float se = 0.f;
#pragma unroll
    for (int i = 0; i < 8; ++i) se += wred[i];

    if (j == 0) srcidx[b * NOUT] = 0;         // cls token always first
    if (j >= 1) {
        if (keep) {
            srcidx[b * NOUT + 1 + cnt] = j;   // positions 1..254, ascending j
        } else {
            int q = (j - 1) - cnt;            // 0..256, ascending j
            otheridx[b * KOTHER + q] = j;
            otherw[b * KOTHER + q] = e / se;
        }
    }
}

// ---------------- K4: gather rows (2/block) + weighted partial sums ----------------
// blocks [0, BATCH*128): each copies out rows 2*ph and 2*ph+1 (row 255
// excluded — written by k5). 384 threads: t<192 -> first row, t>=192 -> second.
// blocks [BATCH*128, +BATCH*8): weighted-sum chunks, 8 per batch, each
// accumulates 32-33 of the 257 softmax terms at full HBM BW (threads 0..191).
__global__ void k4_out(const float* __restrict__ x,
                       const int* __restrict__ srcidx,
                       const int* __restrict__ otheridx,
                       const float* __restrict__ otherw,
                       float* __restrict__ out,
                       float* __restrict__ wpart) {
    int blk = blockIdx.x;
    int t = threadIdx.x;             // 0..383
    const vf4* x4 = (const vf4*)x;
    if (blk < BATCH * 128) {
        int b  = blk >> 7;
        int ph = blk & 127;
        int hi = (t >= 192);
        int p  = (ph << 1) + hi;
        if (p == 255) return;        // upper half of last pair: written by k5
        int tt = t - (hi ? 192 : 0);
        int j = srcidx[b * NOUT + p];
        vf4 v = __builtin_nontemporal_load(&x4[((size_t)b * SEQ + j) * 192 + tt]);
        __builtin_nontemporal_store(v, &((vf4*)out)[((size_t)(b * NOUT + p)) * 192 + tt]);
    } else {
        if (t >= 192) return;
        int widx = blk - BATCH * 128;    // 0..511
        int b = widx >> 3;
        int c = widx & 7;
        int q0 = c ? 32 * c + 1 : 0;     // chunk 0: 33 terms, chunks 1..7: 32
        int qn = c ? 32 : 33;
        vf4 acc = {0.f, 0.f, 0.f, 0.f};
        for (int q = q0; q < q0 + qn; ++q) {
            int   jj = otheridx[b * KOTHER + q];
            float ww = otherw[b * KOTHER + q];
            vf4 xv = __builtin_nontemporal_load(&x4[((size_t)b * SEQ + jj) * 192 + t]);
            acc.x += ww * xv.x; acc.y += ww * xv.y;
            acc.z += ww * xv.z; acc.w += ww * xv.w;
        }
        ((vf4*)wpart)[(size_t)widx * 192 + t] = acc;
    }
}

// ---------------- K5: combine weighted partials into out row 255 ----------------
__global__ void k5_combine(const float* __restrict__ wpart, float* __restrict__ out) {
    int b = blockIdx.x;
    int t = threadIdx.x;             // 0..191
    const vf4* wp4 = (const vf4*)wpart;
    vf4 a = {0.f, 0.f, 0.f, 0.f};
#pragma unroll
    for (int c = 0; c < WCHUNK; ++c) {
        vf4 v = wp4[((size_t)(b * WCHUNK + c)) * 192 + t];
        a.x += v.x; a.y += v.y; a.z += v.z; a.w += v.w;
    }
    const float inv = 1.0f / 257.0f;
    vf4 o = {a.x * inv, a.y * inv, a.z * inv, a.w * inv};
    __builtin_nontemporal_store(o, &((vf4*)out)[((size_t)(b * NOUT + 255)) * 192 + t]);
}

extern "C" void kernel_launch(void* const* d_in, const int* in_sizes, int n_in,
                              void* d_out, int out_size, void* d_ws, size_t ws_size,
                              hipStream_t stream) {
    const float* x     = (const float*)d_in[0];
    const float* atten = (const float*)d_in[1];
    float* out = (float*)d_out;
    char* ws = (char*)d_ws;

    // ws layout (all fully overwritten before read; no init needed)
    float* partial  = (float*)ws;                                     // 3072*512*4 = 6291456 B
    float* dpart    = (float*)(ws + 6291456);                         // 768*512*4  = 1572864 B
    int*   srcidx   = (int*)(ws + 6291456 + 1572864);                 // 64*256*4   = 65536 B
    int*   otheridx = (int*)(ws + 6291456 + 1572864 + 65536);         // 64*257*4   = 65792 B
    float* otherw   = (float*)(ws + 6291456 + 1572864 + 65536 + 65792);            // 65792 B
    float* wpart    = (float*)(ws + 6291456 + 1572864 + 65536 + 65792 + 65792);    // 512*768*4 B

    k1_colsum<<<dim3(BATCH * HEADS * 4), dim3(128), 0, stream>>>(atten, (vf4*)partial, dpart);
    k23_select<<<dim3(BATCH), dim3(SEQ), 0, stream>>>(partial, dpart, srcidx, otheridx, otherw);
    k4_out<<<dim3(BATCH * 128 + BATCH * WCHUNK), dim3(384), 0, stream>>>(
        x, srcidx, otheridx, otherw, out, wpart);
    k5_combine<<<dim3(BATCH), dim3(192), 0, stream>>>(wpart, out);
}